// Round 1
// baseline (600.627 us; speedup 1.0000x reference)
//
#include <hip/hip_runtime.h>
#include <hip/hip_bf16.h>
#include <math.h>

#define NB 32          // batch
#define PP 24564       // priors
#define MM 32          // objects per image
#define NCLS 81
#define CHUNK 1024     // priors per block
#define CBLK 24        // ceil(PP/CHUNK)

// ---- workspace layout (bytes) ----
// [0..15]     float acc[4]: 0=loc_sum 1=ce_sum 2=objpos_sum 3=hn_sum
// [16..19]    int npos_total
// [20..23]    int denom (sum of per-row k)
// [32..159]   int pos_count[NB]
// [256..8447] u64 best_key[NB*MM]
// [16384..]   u32 posmask bits (NB*PP bits = 98256 B)
#define WS_ACC 0
#define WS_NPOS 16
#define WS_DENOM 20
#define WS_PCNT 32
#define WS_BESTKEY 256
#define WS_POSMASK 16384
#define WS_ZERO_BYTES (16384 + 98304)

__device__ __forceinline__ float sl1(float d) {
    float a = fabsf(d);
    return a < 1.0f ? 0.5f * d * d : a - 0.5f;
}

// ---------- Phase 1: per-object argmax over all priors ----------
extern "C" __global__ void __launch_bounds__(256) k_match1(
    const float* __restrict__ priors,
    const float* __restrict__ boxes,
    unsigned long long* __restrict__ best_key)
{
    const int n = blockIdx.y;
    const int t = threadIdx.x;
    __shared__ float bx0[MM], by0[MM], bx1[MM], by1[MM], bar[MM];
    __shared__ unsigned long long sk[MM];
    if (t < MM) {
        const float* b = boxes + ((size_t)n * MM + t) * 4;
        float x1 = b[0], y1 = b[1], x2 = b[2], y2 = b[3];
        bx0[t] = x1; by0[t] = y1; bx1[t] = x2; by1[t] = y2;
        bar[t] = (x2 - x1) * (y2 - y1);
        sk[t] = 0ULL;
    }
    __syncthreads();

    unsigned long long key[MM];
#pragma unroll
    for (int m = 0; m < MM; m++) key[m] = 0ULL;

    const int p0 = blockIdx.x * CHUNK;
    const int pend = min(p0 + CHUNK, PP);
    for (int p = p0 + t; p < pend; p += 256) {
        float4 pb = *(const float4*)(priors + (size_t)p * 4);
        float pa = (pb.z - pb.x) * (pb.w - pb.y);
#pragma unroll
        for (int m = 0; m < MM; m++) {
            float w = fminf(bx1[m], pb.z) - fmaxf(bx0[m], pb.x);
            float h = fminf(by1[m], pb.w) - fmaxf(by0[m], pb.y);
            w = fmaxf(w, 0.0f); h = fmaxf(h, 0.0f);
            float inter = w * h;
            float iou = inter / (bar[m] + pa - inter);
            unsigned long long kk =
                ((unsigned long long)__float_as_uint(iou) << 32) |
                (unsigned long long)(0xFFFFFFFFu - (unsigned)p);
            key[m] = key[m] > kk ? key[m] : kk;
        }
    }
#pragma unroll
    for (int m = 0; m < MM; m++) atomicMax(&sk[m], key[m]);
    __syncthreads();
    if (t < MM) atomicMax(&best_key[n * MM + t], sk[t]);
}

// ---------- Phase 2: per-prior match + positive-only loss partials ----------
extern "C" __global__ void __launch_bounds__(256) k_match2(
    const float* __restrict__ priors,
    const float* __restrict__ boxes,
    const int* __restrict__ labels,
    const float* __restrict__ pred_boxes,
    const float* __restrict__ pred_cls,
    const float* __restrict__ pred_obj,
    const unsigned long long* __restrict__ best_key,
    unsigned int* __restrict__ posmask,
    int* __restrict__ pos_count,
    int* __restrict__ npos_total,
    float* __restrict__ acc)
{
    const int n = blockIdx.y;
    const int t = threadIdx.x;
    __shared__ float bx0[MM], by0[MM], bx1[MM], by1[MM], bar[MM];
    __shared__ float bcx[MM], bcy[MM], bww[MM], bhh[MM];
    __shared__ int lab[MM], pprior[MM];
    if (t < MM) {
        const float* b = boxes + ((size_t)n * MM + t) * 4;
        float x1 = b[0], y1 = b[1], x2 = b[2], y2 = b[3];
        bx0[t] = x1; by0[t] = y1; bx1[t] = x2; by1[t] = y2;
        bar[t] = (x2 - x1) * (y2 - y1);
        bcx[t] = (x1 + x2) * 0.5f; bcy[t] = (y1 + y2) * 0.5f;
        bww[t] = x2 - x1; bhh[t] = y2 - y1;
        lab[t] = labels[n * MM + t];
        pprior[t] = (int)(0xFFFFFFFFu - (unsigned)(best_key[n * MM + t] & 0xFFFFFFFFULL));
    }
    __syncthreads();

    float loc_s = 0.f, ce_s = 0.f, op_s = 0.f, cnt_s = 0.f;
    const int p0 = blockIdx.x * CHUNK;
    const int pend = min(p0 + CHUNK, PP);
    for (int p = p0 + t; p < pend; p += 256) {
        float4 pb = *(const float4*)(priors + (size_t)p * 4);
        float pa = (pb.z - pb.x) * (pb.w - pb.y);
        float best = -1.0f; int bm = 0;
#pragma unroll
        for (int m = 0; m < MM; m++) {
            float w = fminf(bx1[m], pb.z) - fmaxf(bx0[m], pb.x);
            float h = fminf(by1[m], pb.w) - fmaxf(by0[m], pb.y);
            w = fmaxf(w, 0.0f); h = fmaxf(h, 0.0f);
            float inter = w * h;
            float iou = inter / (bar[m] + pa - inter);
            if (iou > best) { best = iou; bm = m; }   // strict > : first-m on ties
        }
        // forced assignment, ascending m => last-wins (scatter order)
#pragma unroll
        for (int m = 0; m < MM; m++) {
            if (pprior[m] == p) { bm = m; best = 1.0f; }
        }
        if (best >= 0.5f) {   // positive iff iou_per_prior >= THRESHOLD
            cnt_s += 1.0f;
            size_t idx = (size_t)n * PP + p;
            atomicOr(&posmask[idx >> 5], 1u << (idx & 31));
            // ---- loc loss (smooth L1 vs encoded gt) ----
            float4 pdb = *(const float4*)(pred_boxes + idx * 4);
            float pcx = (pb.x + pb.z) * 0.5f, pcy = (pb.y + pb.w) * 0.5f;
            float pw = pb.z - pb.x, ph = pb.w - pb.y;
            float g0 = (bcx[bm] - pcx) / (pw / 10.0f);
            float g1 = (bcy[bm] - pcy) / (ph / 10.0f);
            float g2 = logf(bww[bm] / pw) * 5.0f;
            float g3 = logf(bhh[bm] / ph) * 5.0f;
            loc_s += sl1(pdb.x - g0) + sl1(pdb.y - g1) + sl1(pdb.z - g2) + sl1(pdb.w - g3);
            // ---- CE over 81 classes (read only at positives) ----
            const float* row = pred_cls + idx * NCLS;
            float mx = row[0];
            for (int i = 1; i < NCLS; i++) mx = fmaxf(mx, row[i]);
            float se = 0.f;
            for (int i = 0; i < NCLS; i++) se += expf(row[i] - mx);
            ce_s += mx + logf(se) - row[lab[bm]];
            // ---- objectness positive MSE ----
            float o = pred_obj[idx];
            op_s += (o - 1.0f) * (o - 1.0f);
        }
    }

    // block reduce (wave shuffle then LDS)
#pragma unroll
    for (int off = 32; off > 0; off >>= 1) {
        loc_s += __shfl_down(loc_s, off);
        ce_s  += __shfl_down(ce_s,  off);
        op_s  += __shfl_down(op_s,  off);
        cnt_s += __shfl_down(cnt_s, off);
    }
    __shared__ float rl, rc, ro, rn;
    if (t == 0) { rl = 0.f; rc = 0.f; ro = 0.f; rn = 0.f; }
    __syncthreads();
    if ((t & 63) == 0) {
        atomicAdd(&rl, loc_s); atomicAdd(&rc, ce_s);
        atomicAdd(&ro, op_s);  atomicAdd(&rn, cnt_s);
    }
    __syncthreads();
    if (t == 0) {
        if (rl != 0.f) atomicAdd(&acc[0], rl);
        if (rc != 0.f) atomicAdd(&acc[1], rc);
        if (ro != 0.f) atomicAdd(&acc[2], ro);
        int c = (int)rn;
        if (c) { atomicAdd(&pos_count[n], c); atomicAdd(npos_total, c); }
    }
}

// ---------- Hard-negative mining: exact top-k sum via radix select ----------
extern "C" __global__ void __launch_bounds__(256) k_hardneg(
    const float* __restrict__ pred_obj,
    const unsigned int* __restrict__ posmask,
    const int* __restrict__ pos_count,
    float* __restrict__ acc,
    int* __restrict__ denom)
{
    const int n = blockIdx.x;
    const int t = threadIdx.x;
    int k = pos_count[n] * 3;
    if (k > PP) k = PP;
    if (k <= 0) return;   // uniform per block

    __shared__ unsigned int hist[256];
    __shared__ unsigned int s_prefix;
    __shared__ int s_rem;

    unsigned prefix = 0; int rem = k;
    for (int pass = 0; pass < 4; ++pass) {
        const int shift = 24 - 8 * pass;
        for (int i = t; i < 256; i += 256) hist[i] = 0;
        __syncthreads();
        for (int p = t; p < PP; p += 256) {
            size_t idx = (size_t)n * PP + p;
            unsigned m = (posmask[idx >> 5] >> (idx & 31)) & 1u;
            float o = pred_obj[idx];
            float v = m ? 0.0f : o * o;
            unsigned b = __float_as_uint(v);
            if (pass == 0 || (b >> (shift + 8)) == prefix)
                atomicAdd(&hist[(b >> shift) & 0xFFu], 1u);
        }
        __syncthreads();
        if (t == 0) {
            unsigned cum = 0; int d;
            for (d = 255; d > 0; --d) {
                if (cum + hist[d] >= (unsigned)rem) break;
                cum += hist[d];
            }
            s_prefix = (prefix << 8) | (unsigned)d;
            s_rem = rem - (int)cum;
        }
        __syncthreads();
        prefix = s_prefix; rem = s_rem;
        __syncthreads();
    }

    const unsigned thr = prefix;
    const float thrv = __uint_as_float(thr);
    float mysum = 0.f; float mycnt = 0.f;
    for (int p = t; p < PP; p += 256) {
        size_t idx = (size_t)n * PP + p;
        unsigned m = (posmask[idx >> 5] >> (idx & 31)) & 1u;
        float o = pred_obj[idx];
        float v = m ? 0.0f : o * o;
        if (__float_as_uint(v) > thr) { mysum += v; mycnt += 1.0f; }
    }
#pragma unroll
    for (int off = 32; off > 0; off >>= 1) {
        mysum += __shfl_down(mysum, off);
        mycnt += __shfl_down(mycnt, off);
    }
    __shared__ float rs, rc2;
    if (t == 0) { rs = 0.f; rc2 = 0.f; }
    __syncthreads();
    if ((t & 63) == 0) { atomicAdd(&rs, mysum); atomicAdd(&rc2, mycnt); }
    __syncthreads();
    if (t == 0) {
        float total = rs + ((float)k - rc2) * thrv;
        atomicAdd(&acc[3], total);
        atomicAdd(denom, k);
    }
}

// ---------- Finalize ----------
extern "C" __global__ void k_final(const float* __restrict__ acc,
                                   const int* __restrict__ npos,
                                   const int* __restrict__ denom,
                                   float* __restrict__ out)
{
    if (threadIdx.x == 0 && blockIdx.x == 0) {
        float np = (float)(*npos);
        float den = fmaxf((float)(*denom), 1.0f);
        float loc = acc[0] / (np * 4.0f);
        out[0] = acc[1] / np + acc[2] / np + acc[3] / den + loc;
    }
}

extern "C" void kernel_launch(void* const* d_in, const int* in_sizes, int n_in,
                              void* d_out, int out_size, void* d_ws, size_t ws_size,
                              hipStream_t stream) {
    const float* pred_boxes = (const float*)d_in[0];
    const float* pred_cls   = (const float*)d_in[1];
    const float* pred_obj   = (const float*)d_in[2];
    const float* priors     = (const float*)d_in[3];
    const float* boxes      = (const float*)d_in[4];
    const int*   labels     = (const int*)d_in[5];

    char* ws = (char*)d_ws;
    float* acc = (float*)(ws + WS_ACC);
    int* npos  = (int*)(ws + WS_NPOS);
    int* denom = (int*)(ws + WS_DENOM);
    int* pcnt  = (int*)(ws + WS_PCNT);
    unsigned long long* bkey = (unsigned long long*)(ws + WS_BESTKEY);
    unsigned int* posmask = (unsigned int*)(ws + WS_POSMASK);

    hipMemsetAsync(d_ws, 0, WS_ZERO_BYTES, stream);

    dim3 grid(CBLK, NB);
    k_match1<<<grid, 256, 0, stream>>>(priors, boxes, bkey);
    k_match2<<<grid, 256, 0, stream>>>(priors, boxes, labels, pred_boxes, pred_cls,
                                       pred_obj, bkey, posmask, pcnt, npos, acc);
    k_hardneg<<<NB, 256, 0, stream>>>(pred_obj, posmask, pcnt, acc, denom);
    k_final<<<1, 64, 0, stream>>>(acc, npos, denom, (float*)d_out);
}

// Round 2
// 442.516 us; speedup vs baseline: 1.3573x; 1.3573x over previous
//
#include <hip/hip_runtime.h>
#include <math.h>

#define NB 32          // batch
#define PP 24564       // priors
#define MM 32          // objects per image
#define NCLS 81
#define BLOCKS_P 48    // prior-chunks per image
#define CHUNK 512      // priors per block
#define NWAVES 4       // 256 threads

// ---- workspace layout (bytes) ----
// [0..15]     float acc[4]: 0=loc_sum 1=ce_sum 2=objpos_sum 3=hn_sum
// [32..159]   int pos_count[NB]
// [256..8447] u64 best_key[NB*MM]
// [16384..]   u32 posmask bits (NB*PP bits = 98256 B)
#define WS_ACC 0
#define WS_PCNT 32
#define WS_BESTKEY 256
#define WS_POSMASK 16384
#define WS_ZERO_BYTES (16384 + 98304)

__device__ __forceinline__ float sl1(float d) {
    float a = fabsf(d);
    return a < 1.0f ? 0.5f * d * d : a - 0.5f;
}

__device__ __forceinline__ unsigned long long u64max(unsigned long long a, unsigned long long b) {
    return a > b ? a : b;
}

// ---------- Phase 1: per-object argmax over all priors ----------
// lane-parallel: lane's object m = lane&31, halves handle 2 priors per wave-iter.
// Box params live in registers; no LDS/atomics in the hot loop.
extern "C" __global__ void __launch_bounds__(256) k_match1(
    const float* __restrict__ priors,
    const float* __restrict__ boxes,
    unsigned long long* __restrict__ best_key)
{
    const int n = blockIdx.y;
    const int t = threadIdx.x;
    const int lane = t & 63;
    const int wave = t >> 6;
    const int half = lane >> 5;
    const int m = lane & 31;

    const float* b = boxes + ((size_t)n * MM + m) * 4;
    const float bx0 = b[0], by0 = b[1], bx1 = b[2], by1 = b[3];
    const float bar = (bx1 - bx0) * (by1 - by0);

    unsigned long long best = 0ULL;
    const int p0 = blockIdx.x * CHUNK;
    const int pend = min(p0 + CHUNK, PP);
    for (int p = p0 + wave * 2 + half; p < pend; p += NWAVES * 2) {
        float4 pb = *(const float4*)(priors + (size_t)p * 4);
        float w = fminf(bx1, pb.z) - fmaxf(bx0, pb.x);
        float h = fminf(by1, pb.w) - fmaxf(by0, pb.y);
        w = fmaxf(w, 0.0f); h = fmaxf(h, 0.0f);
        float inter = w * h;
        float pa = (pb.z - pb.x) * (pb.w - pb.y);
        float iou = inter / (bar + pa - inter);
        // ties -> smallest p (argmax axis=1 first-index semantics)
        unsigned long long kk = ((unsigned long long)__float_as_uint(iou) << 32)
                              | (unsigned long long)(0xFFFFFFFFu - (unsigned)p);
        best = u64max(best, kk);
    }
    // combine the two halves (same m, disjoint priors)
    best = u64max(best, (unsigned long long)__shfl_xor(best, 32));

    __shared__ unsigned long long wk[NWAVES][MM];
    if (lane < MM) wk[wave][m] = best;
    __syncthreads();
    if (t < MM) {
        unsigned long long r = wk[0][t];
#pragma unroll
        for (int w2 = 1; w2 < NWAVES; w2++) r = u64max(r, wk[w2][t]);
        atomicMax(&best_key[n * MM + t], r);   // native global u64 max, low contention
    }
}

// ---------- Phase 2: per-prior match + positive-only loss partials ----------
extern "C" __global__ void __launch_bounds__(256) k_match2(
    const float* __restrict__ priors,
    const float* __restrict__ boxes,
    const int* __restrict__ labels,
    const float* __restrict__ pred_boxes,
    const float* __restrict__ pred_cls,
    const float* __restrict__ pred_obj,
    const unsigned long long* __restrict__ best_key,
    unsigned int* __restrict__ posmask,
    int* __restrict__ pos_count,
    float* __restrict__ acc)
{
    const int n = blockIdx.y;
    const int t = threadIdx.x;
    const int lane = t & 63;
    const int wave = t >> 6;
    const int half = lane >> 5;
    const int m = lane & 31;

    const float* b = boxes + ((size_t)n * MM + m) * 4;
    const float bx0 = b[0], by0 = b[1], bx1 = b[2], by1 = b[3];
    const float bar = (bx1 - bx0) * (by1 - by0);
    const int pprior = (int)(0xFFFFFFFFu -
        (unsigned)(best_key[n * MM + m] & 0xFFFFFFFFULL));

    float loc_s = 0.f, ce_s = 0.f, op_s = 0.f;
    int cnt = 0;

    const int p0 = blockIdx.x * CHUNK;
    const int pend = min(p0 + CHUNK, PP);
    for (int base = p0 + wave * 2; base < pend; base += NWAVES * 2) {
        const int p = base + half;
        const bool pvalid = p < pend;
        float iou = -1.0f;
        bool forced = false;
        if (pvalid) {
            float4 pb = *(const float4*)(priors + (size_t)p * 4);
            float w = fminf(bx1, pb.z) - fmaxf(bx0, pb.x);
            float h = fminf(by1, pb.w) - fmaxf(by0, pb.y);
            w = fmaxf(w, 0.0f); h = fmaxf(h, 0.0f);
            float inter = w * h;
            float pa = (pb.z - pb.x) * (pb.w - pb.y);
            iou = inter / (bar + pa - inter);
            forced = (pprior == p);
        }
        // positive iff max-iou >= 0.5 or any forced assignment: skip the
        // reduction entirely for all-negative prior pairs (the common case)
        if (!__any(forced || iou >= 0.5f)) continue;

        // per-half argmax over m. natural ties -> smallest m (argmax axis=0);
        // forced overrides beat everything; multiple forced -> largest m (scatter last-wins)
        unsigned long long key = 0ULL;
        if (pvalid) {
            key = forced ? ((1ULL << 63) | (unsigned long long)m)
                         : (((unsigned long long)__float_as_uint(iou) << 32)
                            | (unsigned long long)(31 - m));
        }
#pragma unroll
        for (int d = 1; d < 32; d <<= 1)
            key = u64max(key, (unsigned long long)__shfl_xor(key, d));

        // process the (up to 2) positive priors in this pair, wave-cooperatively
        for (int h2 = 0; h2 < 2; ++h2) {
            unsigned long long k2 = (unsigned long long)__shfl(key, h2 * 32);
            const int pc = base + h2;
            if (pc >= pend) continue;
            int bm; float iouw;
            if (k2 >> 63) { bm = (int)(k2 & 0x3FULL); iouw = 1.0f; }
            else { bm = 31 - (int)(k2 & 0xFFFFFFFFULL);
                   iouw = __uint_as_float((unsigned)(k2 >> 32)); }
            if (!(iouw >= 0.5f)) continue;

            const size_t idx = (size_t)n * PP + pc;
            // CE over 81 classes, all 64 lanes cooperate (coalesced row read)
            const float* row = pred_cls + idx * NCLS;
            float a = row[lane];
            float b2 = (lane + 64 < NCLS) ? row[lane + 64] : -INFINITY;
            float mx = fmaxf(a, b2);
#pragma unroll
            for (int d = 1; d < 64; d <<= 1) mx = fmaxf(mx, __shfl_xor(mx, d));
            float se = expf(a - mx) + ((lane + 64 < NCLS) ? expf(b2 - mx) : 0.f);
#pragma unroll
            for (int d = 1; d < 64; d <<= 1) se += __shfl_xor(se, d);

            if (lane == 0) {
                cnt++;
                atomicOr(&posmask[idx >> 5], 1u << (idx & 31));
                const int lb = labels[n * MM + bm];
                ce_s += mx + logf(se) - row[lb];
                // loc loss (smooth L1 vs encoded gt)
                const float* bb = boxes + ((size_t)n * MM + bm) * 4;
                float gx1 = bb[0], gy1 = bb[1], gx2 = bb[2], gy2 = bb[3];
                float4 pbc = *(const float4*)(priors + (size_t)pc * 4);
                float pcx = (pbc.x + pbc.z) * 0.5f, pcy = (pbc.y + pbc.w) * 0.5f;
                float pw = pbc.z - pbc.x, ph = pbc.w - pbc.y;
                float g0 = ((gx1 + gx2) * 0.5f - pcx) / (pw / 10.0f);
                float g1 = ((gy1 + gy2) * 0.5f - pcy) / (ph / 10.0f);
                float g2 = logf((gx2 - gx1) / pw) * 5.0f;
                float g3 = logf((gy2 - gy1) / ph) * 5.0f;
                float4 pdb = *(const float4*)(pred_boxes + idx * 4);
                loc_s += sl1(pdb.x - g0) + sl1(pdb.y - g1)
                       + sl1(pdb.z - g2) + sl1(pdb.w - g3);
                float o = pred_obj[idx];
                op_s += (o - 1.0f) * (o - 1.0f);
            }
        }
    }

    // per-wave lane0 holds this wave's partials; only non-empty waves touch globals
    if (lane == 0 && cnt > 0) {
        atomicAdd(&acc[0], loc_s);
        atomicAdd(&acc[1], ce_s);
        atomicAdd(&acc[2], op_s);
        atomicAdd(&pos_count[n], cnt);
    }
}

// ---------- Hard-negative mining: exact top-k sum via radix select ----------
extern "C" __global__ void __launch_bounds__(256) k_hardneg(
    const float* __restrict__ pred_obj,
    const unsigned int* __restrict__ posmask,
    const int* __restrict__ pos_count,
    float* __restrict__ acc)
{
    const int n = blockIdx.x;
    const int t = threadIdx.x;
    const int wave = t >> 6;
    int k = pos_count[n] * 3;
    if (k > PP) k = PP;
    if (k <= 0) return;   // uniform per block

    __shared__ unsigned int hist[NWAVES][256];
    __shared__ unsigned int s_prefix;
    __shared__ int s_rem;

    unsigned prefix = 0; int rem = k;
    for (int pass = 0; pass < 4; ++pass) {
        const int shift = 24 - 8 * pass;
        for (int i = t; i < NWAVES * 256; i += 256) hist[i >> 8][i & 255] = 0;
        __syncthreads();
        for (int p = t; p < PP; p += 256) {
            size_t idx = (size_t)n * PP + p;
            unsigned msk = (posmask[idx >> 5] >> (idx & 31)) & 1u;
            float o = pred_obj[idx];
            float v = msk ? 0.0f : o * o;
            unsigned bb = __float_as_uint(v);
            if (pass == 0 || (bb >> (shift + 8)) == prefix)
                atomicAdd(&hist[wave][(bb >> shift) & 0xFFu], 1u);
        }
        __syncthreads();
        if (t == 0) {
            unsigned cum = 0; int d;
            for (d = 255; d > 0; --d) {
                unsigned hd = hist[0][d] + hist[1][d] + hist[2][d] + hist[3][d];
                if (cum + hd >= (unsigned)rem) break;
                cum += hd;
            }
            s_prefix = (prefix << 8) | (unsigned)d;
            s_rem = rem - (int)cum;
        }
        __syncthreads();
        prefix = s_prefix; rem = s_rem;
        __syncthreads();
    }

    const unsigned thr = prefix;
    const float thrv = __uint_as_float(thr);
    float mysum = 0.f, mycnt = 0.f;
    for (int p = t; p < PP; p += 256) {
        size_t idx = (size_t)n * PP + p;
        unsigned msk = (posmask[idx >> 5] >> (idx & 31)) & 1u;
        float o = pred_obj[idx];
        float v = msk ? 0.0f : o * o;
        if (__float_as_uint(v) > thr) { mysum += v; mycnt += 1.0f; }
    }
#pragma unroll
    for (int off = 32; off > 0; off >>= 1) {
        mysum += __shfl_down(mysum, off);
        mycnt += __shfl_down(mycnt, off);
    }
    __shared__ float rs, rc2;
    if (t == 0) { rs = 0.f; rc2 = 0.f; }
    __syncthreads();
    if ((t & 63) == 0) { atomicAdd(&rs, mysum); atomicAdd(&rc2, mycnt); }
    __syncthreads();
    if (t == 0) atomicAdd(&acc[3], rs + ((float)k - rc2) * thrv);
}

// ---------- Finalize ----------
extern "C" __global__ void k_final(const float* __restrict__ acc,
                                   const int* __restrict__ pcnt,
                                   float* __restrict__ out)
{
    if (threadIdx.x == 0 && blockIdx.x == 0) {
        int np = 0, den = 0;
        for (int i = 0; i < NB; i++) {
            int c = pcnt[i];
            np += c;
            int k = c * 3; if (k > PP) k = PP;
            den += k;
        }
        float npf = (float)np;
        out[0] = acc[1] / npf + acc[2] / npf
               + acc[3] / fmaxf((float)den, 1.0f)
               + acc[0] / (npf * 4.0f);
    }
}

extern "C" void kernel_launch(void* const* d_in, const int* in_sizes, int n_in,
                              void* d_out, int out_size, void* d_ws, size_t ws_size,
                              hipStream_t stream) {
    const float* pred_boxes = (const float*)d_in[0];
    const float* pred_cls   = (const float*)d_in[1];
    const float* pred_obj   = (const float*)d_in[2];
    const float* priors     = (const float*)d_in[3];
    const float* boxes      = (const float*)d_in[4];
    const int*   labels     = (const int*)d_in[5];

    char* ws = (char*)d_ws;
    float* acc = (float*)(ws + WS_ACC);
    int* pcnt  = (int*)(ws + WS_PCNT);
    unsigned long long* bkey = (unsigned long long*)(ws + WS_BESTKEY);
    unsigned int* posmask = (unsigned int*)(ws + WS_POSMASK);

    hipMemsetAsync(d_ws, 0, WS_ZERO_BYTES, stream);

    dim3 grid(BLOCKS_P, NB);
    k_match1<<<grid, 256, 0, stream>>>(priors, boxes, bkey);
    k_match2<<<grid, 256, 0, stream>>>(priors, boxes, labels, pred_boxes, pred_cls,
                                       pred_obj, bkey, posmask, pcnt, acc);
    k_hardneg<<<NB, 256, 0, stream>>>(pred_obj, posmask, pcnt, acc);
    k_final<<<1, 64, 0, stream>>>(acc, pcnt, (float*)d_out);
}

// Round 3
// 244.271 us; speedup vs baseline: 2.4589x; 1.8116x over previous
//
#include <hip/hip_runtime.h>
#include <math.h>

#define NB 32          // batch
#define PP 24564       // priors
#define MM 32          // objects per image
#define NCLS 81
#define CHUNK 1024     // priors per k_match block
#define MBLK 24        // ceil(PP/CHUNK)
#define PBLK 96        // k_pos blocks per image (96*256 = 24576)
#define PPW 768        // posbit u32 words per image (24576 bits)

// ---- workspace layout (bytes) ----
#define WS_ACC 0          // float[4]: 0=loc 1=ce 2=objpos 3=hardneg
#define WS_PCNT 32        // int[NB]
#define WS_BKEY 256       // u64[NB*MM]
#define WS_FLIST 8448     // u32[NB*MM]  (p<<5)|m, ascending m = last-wins
#define WS_M8 16384       // u8[NB*PP] natural match m per prior
#define WS_POSBIT 802816  // u32[NB*PPW] final positive bits
#define WS_ZERO 8448      // zero acc, pcnt, bkey only

__device__ __forceinline__ float sl1(float d) {
    float a = fabsf(d);
    return a < 1.0f ? 0.5f * d * d : a - 0.5f;
}
__device__ __forceinline__ unsigned long long u64max(unsigned long long a, unsigned long long b) {
    return a > b ? a : b;
}

// ---------- Fused matching: per-prior argmax (thread-local) + per-object argmax ----------
extern "C" __global__ void __launch_bounds__(256) k_match(
    const float* __restrict__ priors,
    const float* __restrict__ boxes,
    unsigned long long* __restrict__ bkey,
    unsigned char* __restrict__ m8,
    unsigned int* __restrict__ posbit,
    int* __restrict__ pcnt)
{
    const int n = blockIdx.y;
    const int t = threadIdx.x;
    const int lane = t & 63;
    const int wave = t >> 6;
    const int p0 = blockIdx.x * CHUNK;

    __shared__ float4 spri[CHUNK];                 // 16 KB
    __shared__ float bx0[MM], by0[MM], bx1[MM], by1[MM], bar_[MM];
    __shared__ unsigned long long wk[4][MM];

    // stage priors chunk (coalesced); pad OOB with a far-away dummy (iou = 0)
#pragma unroll
    for (int i = 0; i < 4; i++) {
        int p = p0 + t + i * 256;
        float4 v;
        if (p < PP) v = *(const float4*)(priors + (size_t)p * 4);
        else { v.x = 3.f; v.y = 3.f; v.z = 3.5f; v.w = 3.5f; }
        spri[t + i * 256] = v;
    }
    if (t < MM) {
        const float* b = boxes + ((size_t)n * MM + t) * 4;
        float x1 = b[0], y1 = b[1], x2 = b[2], y2 = b[3];
        bx0[t] = x1; by0[t] = y1; bx1[t] = x2; by1[t] = y2;
        bar_[t] = (x2 - x1) * (y2 - y1);
    }
    __syncthreads();

    float4 pr0 = spri[t], pr1 = spri[t + 256], pr2 = spri[t + 512], pr3 = spri[t + 768];
    const float pa0 = (pr0.z - pr0.x) * (pr0.w - pr0.y);
    const float pa1 = (pr1.z - pr1.x) * (pr1.w - pr1.y);
    const float pa2 = (pr2.z - pr2.x) * (pr2.w - pr2.y);
    const float pa3 = (pr3.z - pr3.x) * (pr3.w - pr3.y);
    unsigned pb0 = 0, pb1 = 0, pb2 = 0, pb3 = 0;   // per-prior keys: trunc-iou | (31-m)

#define DO_IOU(PR, PA, PB, ROFF) { \
        float w = fminf(x1, PR.z) - fmaxf(x0, PR.x); \
        float h = fminf(y1, PR.w) - fmaxf(y0, PR.y); \
        w = fmaxf(w, 0.0f); h = fmaxf(h, 0.0f); \
        float inter = w * h; \
        float iou = inter / (ar + PA - inter); \
        unsigned ib = __float_as_uint(iou); \
        unsigned nk = (ib & 0xFFFFFFE0u) | (unsigned)(31 - m); \
        PB = PB > nk ? PB : nk; \
        unsigned long long kk = ((unsigned long long)ib << 32) \
            | (unsigned long long)(0xFFFFFFFFu - (unsigned)(p0 + t + (ROFF))); \
        km = u64max(km, kk); }

#pragma unroll 2
    for (int m = 0; m < MM; m++) {
        const float x0 = bx0[m], y0 = by0[m], x1 = bx1[m], y1 = by1[m], ar = bar_[m];
        unsigned long long km = 0ULL;
        DO_IOU(pr0, pa0, pb0, 0)
        DO_IOU(pr1, pa1, pb1, 256)
        DO_IOU(pr2, pa2, pb2, 512)
        DO_IOU(pr3, pa3, pb3, 768)
        // per-object wave reduce (64 lanes = 256 priors)
#pragma unroll
        for (int d = 1; d < 64; d <<= 1)
            km = u64max(km, (unsigned long long)__shfl_xor(km, d));
        if (lane == 0) wk[wave][m] = km;
    }
#undef DO_IOU

    // per-prior outputs: natural match byte + positive bits + count
    int cnt = 0;
    unsigned long long ball;
#define EMIT(PB, R) { \
        int p = p0 + t + (R) * 256; \
        bool pos = (PB >= 0x3F000000u) && (p < PP); \
        if (p < PP) m8[(size_t)n * PP + p] = (unsigned char)(31u - (PB & 31u)); \
        ball = __ballot(pos); \
        if (lane == 0) { \
            int wi = n * PPW + ((p0 + (R) * 256 + wave * 64) >> 5); \
            posbit[wi]     = (unsigned)ball; \
            posbit[wi + 1] = (unsigned)(ball >> 32); \
            cnt += __popcll(ball); \
        } }
    EMIT(pb0, 0) EMIT(pb1, 1) EMIT(pb2, 2) EMIT(pb3, 3)
#undef EMIT
    if (lane == 0 && cnt) atomicAdd(&pcnt[n], cnt);

    __syncthreads();
    if (t < MM) {
        unsigned long long r = u64max(u64max(wk[0][t], wk[1][t]),
                                      u64max(wk[2][t], wk[3][t]));
        atomicMax(&bkey[n * MM + t], r);
    }
}

// ---------- Forced-assignment overrides (tiny) ----------
extern "C" __global__ void k_force(
    const unsigned long long* __restrict__ bkey,
    unsigned int* __restrict__ flist,
    unsigned int* __restrict__ posbit,
    int* __restrict__ pcnt)
{
    int t = threadIdx.x;          // 1024 = NB*MM
    if (t >= NB * MM) return;
    int n = t >> 5, m = t & 31;
    unsigned p = 0xFFFFFFFFu - (unsigned)(bkey[t] & 0xFFFFFFFFULL);
    flist[t] = (p << 5) | (unsigned)m;
    unsigned bit = 1u << (p & 31);
    unsigned old = atomicOr(&posbit[n * PPW + (p >> 5)], bit);
    if (!(old & bit)) atomicAdd(&pcnt[n], 1);
}

// ---------- Positive-prior losses: wave scans 64 priors' bits, cooperates per positive ----------
extern "C" __global__ void __launch_bounds__(256) k_pos(
    const float* __restrict__ pred_boxes,
    const float* __restrict__ pred_cls,
    const float* __restrict__ pred_obj,
    const float* __restrict__ priors,
    const float* __restrict__ boxes,
    const int* __restrict__ labels,
    const unsigned char* __restrict__ m8,
    const unsigned int* __restrict__ posbit,
    const unsigned int* __restrict__ flist,
    float* __restrict__ acc)
{
    const int n = blockIdx.y;
    const int t = threadIdx.x;
    const int lane = t & 63;
    const int wave = t >> 6;
    __shared__ unsigned int fl[MM];
    __shared__ float sacc[3];
    if (t < MM) fl[t] = flist[n * MM + t];
    if (t < 3) sacc[t] = 0.f;
    __syncthreads();

    const int base = blockIdx.x * 256 + wave * 64;
    const int w0 = n * PPW + (base >> 5);
    unsigned long long mask = (unsigned long long)posbit[w0]
                            | ((unsigned long long)posbit[w0 + 1] << 32);

    float ce_s = 0.f, loc_s = 0.f, op_s = 0.f;
    while (mask) {
        int i = __ffsll((long long)mask) - 1;
        mask &= mask - 1;
        const int p = base + i;
        const size_t idx = (size_t)n * PP + p;
        // resolve match: natural byte, then forced overrides (ascending m = last-wins)
        int bm = m8[idx];
#pragma unroll
        for (int j = 0; j < MM; j++) {
            unsigned f = fl[j];
            if ((int)(f >> 5) == p) bm = (int)(f & 31u);
        }
        // CE over 81 classes: coalesced row read + wave log-sum-exp
        const float* row = pred_cls + idx * NCLS;
        float a = row[lane];
        float b = (lane < NCLS - 64) ? row[lane + 64] : -INFINITY;
        float mx = fmaxf(a, b);
#pragma unroll
        for (int d = 1; d < 64; d <<= 1) mx = fmaxf(mx, __shfl_xor(mx, d));
        float se = expf(a - mx) + ((lane < NCLS - 64) ? expf(b - mx) : 0.f);
#pragma unroll
        for (int d = 1; d < 64; d <<= 1) se += __shfl_xor(se, d);

        if (lane == 0) {
            int lb = labels[n * MM + bm];
            ce_s += mx + logf(se) - row[lb];
        } else if (lane == 1) {
            float4 pb = *(const float4*)(priors + (size_t)p * 4);
            const float* bb = boxes + ((size_t)n * MM + bm) * 4;
            float gx1 = bb[0], gy1 = bb[1], gx2 = bb[2], gy2 = bb[3];
            float pcx = (pb.x + pb.z) * 0.5f, pcy = (pb.y + pb.w) * 0.5f;
            float pw = pb.z - pb.x, ph = pb.w - pb.y;
            float g0 = ((gx1 + gx2) * 0.5f - pcx) / (pw / 10.0f);
            float g1 = ((gy1 + gy2) * 0.5f - pcy) / (ph / 10.0f);
            float g2 = logf((gx2 - gx1) / pw) * 5.0f;
            float g3 = logf((gy2 - gy1) / ph) * 5.0f;
            float4 pd = *(const float4*)(pred_boxes + idx * 4);
            loc_s += sl1(pd.x - g0) + sl1(pd.y - g1) + sl1(pd.z - g2) + sl1(pd.w - g3);
        } else if (lane == 2) {
            float o = pred_obj[idx];
            op_s += (o - 1.0f) * (o - 1.0f);
        }
    }
    if (lane == 0 && ce_s != 0.f)  atomicAdd(&sacc[0], ce_s);
    if (lane == 1 && loc_s != 0.f) atomicAdd(&sacc[1], loc_s);
    if (lane == 2 && op_s != 0.f)  atomicAdd(&sacc[2], op_s);
    __syncthreads();
    if (t == 0) {
        if (sacc[0] != 0.f) atomicAdd(&acc[1], sacc[0]);
        if (sacc[1] != 0.f) atomicAdd(&acc[0], sacc[1]);
        if (sacc[2] != 0.f) atomicAdd(&acc[2], sacc[2]);
    }
}

// ---------- Hard-negative mining ----------
extern "C" __global__ void __launch_bounds__(1024) k_hardneg(
    const float* __restrict__ pred_obj,
    const unsigned int* __restrict__ posbit,
    const int* __restrict__ pcnt,
    float* __restrict__ acc)
{
    const int n = blockIdx.x;
    const int t = threadIdx.x;
    const int wave = t >> 6;
    int k = pcnt[n] * 3;
    if (k > PP) k = PP;
    if (k <= 0) return;   // uniform
    const float* obj = pred_obj + (size_t)n * PP;
    const unsigned int* pb = posbit + n * PPW;

    __shared__ float wsum[16], wcnt[16];

    if (k >= PP) {
        // hmask covers everything: sum all neg values (positives contribute 0)
        float s = 0.f;
        for (int p = t; p < PP; p += 1024) {
            unsigned msk = (pb[p >> 5] >> (p & 31)) & 1u;
            float o = obj[p];
            s += msk ? 0.f : o * o;
        }
#pragma unroll
        for (int d = 32; d > 0; d >>= 1) s += __shfl_down(s, d);
        if ((t & 63) == 0) wsum[wave] = s;
        __syncthreads();
        if (t == 0) {
            float tot = 0.f;
            for (int i = 0; i < 16; i++) tot += wsum[i];
            atomicAdd(&acc[3], tot);
        }
        return;
    }

    __shared__ unsigned int hist[16][256];
    __shared__ unsigned int hsum[256];
    __shared__ unsigned int s_prefix;
    __shared__ int s_rem;

    unsigned prefix = 0; int rem = k;
    for (int pass = 0; pass < 4; ++pass) {
        const int shift = 24 - 8 * pass;
        for (int i = t; i < 16 * 256; i += 1024) ((unsigned*)hist)[i] = 0;
        __syncthreads();
        for (int p = t; p < PP; p += 1024) {
            unsigned msk = (pb[p >> 5] >> (p & 31)) & 1u;
            float o = obj[p];
            float v = msk ? 0.f : o * o;
            unsigned bb = __float_as_uint(v);
            if (pass == 0 || (bb >> (shift + 8)) == prefix)
                atomicAdd(&hist[wave][(bb >> shift) & 0xFFu], 1u);
        }
        __syncthreads();
        if (t < 256) {
            unsigned s2 = 0;
            for (int w2 = 0; w2 < 16; w2++) s2 += hist[w2][t];
            hsum[t] = s2;
        }
        __syncthreads();
        if (t == 0) {
            unsigned cum = 0; int d;
            for (d = 255; d > 0; --d) {
                if (cum + hsum[d] >= (unsigned)rem) break;
                cum += hsum[d];
            }
            s_prefix = (prefix << 8) | (unsigned)d;
            s_rem = rem - (int)cum;
        }
        __syncthreads();
        prefix = s_prefix; rem = s_rem;
        __syncthreads();
    }

    const unsigned thr = prefix;
    const float thrv = __uint_as_float(thr);
    float mysum = 0.f, mycnt = 0.f;
    for (int p = t; p < PP; p += 1024) {
        unsigned msk = (pb[p >> 5] >> (p & 31)) & 1u;
        float o = obj[p];
        float v = msk ? 0.f : o * o;
        if (__float_as_uint(v) > thr) { mysum += v; mycnt += 1.f; }
    }
#pragma unroll
    for (int d = 32; d > 0; d >>= 1) {
        mysum += __shfl_down(mysum, d);
        mycnt += __shfl_down(mycnt, d);
    }
    if ((t & 63) == 0) { wsum[wave] = mysum; wcnt[wave] = mycnt; }
    __syncthreads();
    if (t == 0) {
        float ts = 0.f, tc = 0.f;
        for (int i = 0; i < 16; i++) { ts += wsum[i]; tc += wcnt[i]; }
        atomicAdd(&acc[3], ts + ((float)k - tc) * thrv);
    }
}

// ---------- Finalize ----------
extern "C" __global__ void k_final(const float* __restrict__ acc,
                                   const int* __restrict__ pcnt,
                                   float* __restrict__ out)
{
    if (threadIdx.x == 0 && blockIdx.x == 0) {
        int np = 0, den = 0;
        for (int i = 0; i < NB; i++) {
            int c = pcnt[i];
            np += c;
            int k = c * 3; if (k > PP) k = PP;
            den += k;
        }
        float npf = (float)np;
        out[0] = acc[1] / npf + acc[2] / npf
               + acc[3] / fmaxf((float)den, 1.0f)
               + acc[0] / (npf * 4.0f);
    }
}

extern "C" void kernel_launch(void* const* d_in, const int* in_sizes, int n_in,
                              void* d_out, int out_size, void* d_ws, size_t ws_size,
                              hipStream_t stream) {
    const float* pred_boxes = (const float*)d_in[0];
    const float* pred_cls   = (const float*)d_in[1];
    const float* pred_obj   = (const float*)d_in[2];
    const float* priors     = (const float*)d_in[3];
    const float* boxes      = (const float*)d_in[4];
    const int*   labels     = (const int*)d_in[5];

    char* ws = (char*)d_ws;
    float* acc = (float*)(ws + WS_ACC);
    int* pcnt  = (int*)(ws + WS_PCNT);
    unsigned long long* bkey = (unsigned long long*)(ws + WS_BKEY);
    unsigned int* flist = (unsigned int*)(ws + WS_FLIST);
    unsigned char* m8 = (unsigned char*)(ws + WS_M8);
    unsigned int* posbit = (unsigned int*)(ws + WS_POSBIT);

    hipMemsetAsync(d_ws, 0, WS_ZERO, stream);

    k_match<<<dim3(MBLK, NB), 256, 0, stream>>>(priors, boxes, bkey, m8, posbit, pcnt);
    k_force<<<1, 1024, 0, stream>>>(bkey, flist, posbit, pcnt);
    k_pos<<<dim3(PBLK, NB), 256, 0, stream>>>(pred_boxes, pred_cls, pred_obj,
                                              priors, boxes, labels, m8, posbit, flist, acc);
    k_hardneg<<<NB, 1024, 0, stream>>>(pred_obj, posbit, pcnt, acc);
    k_final<<<1, 64, 0, stream>>>(acc, pcnt, (float*)d_out);
}

// Round 4
// 209.349 us; speedup vs baseline: 2.8690x; 1.1668x over previous
//
#include <hip/hip_runtime.h>
#include <math.h>

#define NB 32          // batch
#define PP 24564       // priors
#define MM 32          // objects per image
#define NCLS 81
#define CHUNK 1024     // priors per k_match block
#define MBLK 24        // ceil(PP/CHUNK)
#define PPW 768        // posbit u32 words per image
#define POSBLK_X 64    // k_pos blocks per image

// ---- workspace layout (bytes) ----
#define WS_ACC 0          // float[4]: 0=loc 1=ce 2=objpos 3=hardneg
#define WS_PCNT 32        // int[NB]: positive count / list length per image
#define WS_BKEY 256       // u64[NB*MM] per-object best (iou,~p) keys
#define WS_FLIST 8448     // u32[NB*MM] forced prior per object
#define WS_POSBIT 16384   // u32[NB*PPW] positive bitmask (fully rewritten)
#define WS_PLIST 114688   // u32[NB*PP] compacted positives: p | (m<<16)
#define WS_ZERO_WORDS (8448 / 4)   // zero acc, pcnt, bkey only

__device__ __forceinline__ float sl1(float d) {
    float a = fabsf(d);
    return a < 1.0f ? 0.5f * d * d : a - 0.5f;
}
__device__ __forceinline__ unsigned long long u64max(unsigned long long a, unsigned long long b) {
    return a > b ? a : b;
}

// ---------- Zero the small accumulator region (replaces pathological memset) ----------
extern "C" __global__ void __launch_bounds__(256) k_zero(unsigned int* __restrict__ ws) {
    for (int i = threadIdx.x; i < WS_ZERO_WORDS; i += 256) ws[i] = 0;
}

// ---------- Fused matching: per-prior + per-object argmax, compacted positive list ----------
extern "C" __global__ void __launch_bounds__(256) k_match(
    const float* __restrict__ priors,
    const float* __restrict__ boxes,
    unsigned long long* __restrict__ bkey,
    unsigned int* __restrict__ posbit,
    unsigned int* __restrict__ plist,
    int* __restrict__ pcnt)
{
    const int n = blockIdx.y;
    const int t = threadIdx.x;
    const int lane = t & 63;
    const int wave = t >> 6;
    const int p0 = blockIdx.x * CHUNK;

    __shared__ float4 spri[CHUNK];                 // 16 KB
    __shared__ float bx0[MM], by0[MM], bx1[MM], by1[MM], bar_[MM];
    __shared__ unsigned long long wk[4][MM];

#pragma unroll
    for (int i = 0; i < 4; i++) {
        int p = p0 + t + i * 256;
        float4 v;
        if (p < PP) v = *(const float4*)(priors + (size_t)p * 4);
        else { v.x = 3.f; v.y = 3.f; v.z = 3.5f; v.w = 3.5f; }   // dummy, iou=0
        spri[t + i * 256] = v;
    }
    if (t < MM) {
        const float* b = boxes + ((size_t)n * MM + t) * 4;
        float x1 = b[0], y1 = b[1], x2 = b[2], y2 = b[3];
        bx0[t] = x1; by0[t] = y1; bx1[t] = x2; by1[t] = y2;
        bar_[t] = (x2 - x1) * (y2 - y1);
    }
    __syncthreads();

    float4 pr0 = spri[t], pr1 = spri[t + 256], pr2 = spri[t + 512], pr3 = spri[t + 768];
    const float pa0 = (pr0.z - pr0.x) * (pr0.w - pr0.y);
    const float pa1 = (pr1.z - pr1.x) * (pr1.w - pr1.y);
    const float pa2 = (pr2.z - pr2.x) * (pr2.w - pr2.y);
    const float pa3 = (pr3.z - pr3.x) * (pr3.w - pr3.y);
    unsigned pb0 = 0, pb1 = 0, pb2 = 0, pb3 = 0;   // per-prior keys: trunc-iou | (31-m)

#define DO_IOU(PR, PA, PB, ROFF) { \
        float w = fminf(x1, PR.z) - fmaxf(x0, PR.x); \
        float h = fminf(y1, PR.w) - fmaxf(y0, PR.y); \
        w = fmaxf(w, 0.0f); h = fmaxf(h, 0.0f); \
        float inter = w * h; \
        float iou = inter / (ar + PA - inter); \
        unsigned ib = __float_as_uint(iou); \
        unsigned nk = (ib & 0xFFFFFFE0u) | (unsigned)(31 - m); \
        PB = PB > nk ? PB : nk; \
        unsigned long long kk = ((unsigned long long)ib << 32) \
            | (unsigned long long)(0xFFFFFFFFu - (unsigned)(p0 + t + (ROFF))); \
        km = u64max(km, kk); }

#pragma unroll 2
    for (int m = 0; m < MM; m++) {
        const float x0 = bx0[m], y0 = by0[m], x1 = bx1[m], y1 = by1[m], ar = bar_[m];
        unsigned long long km = 0ULL;
        DO_IOU(pr0, pa0, pb0, 0)
        DO_IOU(pr1, pa1, pb1, 256)
        DO_IOU(pr2, pa2, pb2, 512)
        DO_IOU(pr3, pa3, pb3, 768)
#pragma unroll
        for (int d = 1; d < 64; d <<= 1)
            km = u64max(km, (unsigned long long)__shfl_xor(km, d));
        if (lane == 0) wk[wave][m] = km;
    }
#undef DO_IOU

    // per-prior outputs: positive bits (plain stores) + compacted list entries
    const unsigned long long lm = (1ULL << lane) - 1ULL;
    unsigned long long bl[4]; bool pf[4]; unsigned pv[4]; int cw[4];
#define ROWOUT(PB, R) { \
        int p = p0 + t + (R) * 256; \
        bool pos = (PB >= 0x3F000000u) && (p < PP); \
        unsigned long long ball = __ballot(pos); \
        if (lane == 0) { \
            int wi = n * PPW + ((p0 + (R) * 256 + wave * 64) >> 5); \
            posbit[wi] = (unsigned)ball; posbit[wi + 1] = (unsigned)(ball >> 32); \
        } \
        bl[R] = ball; pf[R] = pos; cw[R] = __popcll(ball); \
        pv[R] = (unsigned)p | ((31u - (PB & 31u)) << 16); }
    ROWOUT(pb0, 0) ROWOUT(pb1, 1) ROWOUT(pb2, 2) ROWOUT(pb3, 3)
#undef ROWOUT

    int tot = cw[0] + cw[1] + cw[2] + cw[3];
    int base = 0;
    if (lane == 0 && tot) base = atomicAdd(&pcnt[n], tot);
    base = __shfl(base, 0);
    unsigned* pl = plist + (size_t)n * PP;
    int b = base;
#pragma unroll
    for (int r = 0; r < 4; r++) {
        if (pf[r]) pl[b + __popcll(bl[r] & lm)] = pv[r];
        b += cw[r];
    }

    __syncthreads();
    if (t < MM) {
        unsigned long long r = u64max(u64max(wk[0][t], wk[1][t]),
                                      u64max(wk[2][t], wk[3][t]));
        atomicMax(&bkey[n * MM + t], r);
    }
}

// ---------- Forced-assignment overrides ----------
extern "C" __global__ void k_force(
    const unsigned long long* __restrict__ bkey,
    unsigned int* __restrict__ flist,
    unsigned int* __restrict__ posbit,
    unsigned int* __restrict__ plist,
    int* __restrict__ pcnt)
{
    int t = threadIdx.x;          // 1024 = NB*MM
    if (t >= NB * MM) return;
    int n = t >> 5, m = t & 31;
    unsigned p = 0xFFFFFFFFu - (unsigned)(bkey[t] & 0xFFFFFFFFULL);
    flist[t] = p;
    unsigned bit = 1u << (p & 31);
    unsigned old = atomicOr(&posbit[n * PPW + (p >> 5)], bit);
    if (!(old & bit)) {   // not naturally positive: append (m fixed later by fl scan)
        int pos = atomicAdd(&pcnt[n], 1);
        plist[(size_t)n * PP + pos] = p | ((unsigned)m << 16);
    }
}

// ---------- Positive-prior losses: one wave per positive, dense list ----------
extern "C" __global__ void __launch_bounds__(256) k_pos(
    const float* __restrict__ pred_boxes,
    const float* __restrict__ pred_cls,
    const float* __restrict__ pred_obj,
    const float* __restrict__ priors,
    const float* __restrict__ boxes,
    const int* __restrict__ labels,
    const unsigned int* __restrict__ plist,
    const unsigned int* __restrict__ flist,
    const int* __restrict__ pcnt,
    float* __restrict__ acc)
{
    const int n = blockIdx.y;
    const int t = threadIdx.x;
    const int lane = t & 63;
    const int wave = t >> 6;
    __shared__ unsigned int fl[MM];
    __shared__ float sacc[3];
    if (t < MM) fl[t] = flist[n * MM + t];
    if (t < 3) sacc[t] = 0.f;
    __syncthreads();

    const int cnt = pcnt[n];
    const unsigned* pl = plist + (size_t)n * PP;
    float ce_s = 0.f, loc_s = 0.f, op_s = 0.f;

    for (int i = blockIdx.x * 4 + wave; i < cnt; i += POSBLK_X * 4) {
        const unsigned e = pl[i];
        const int p = (int)(e & 0xFFFFu);
        int bm = (int)((e >> 16) & 31u);
#pragma unroll
        for (int j = 0; j < MM; j++)
            if (fl[j] == (unsigned)p) bm = j;   // ascending j = last-wins
        const size_t idx = (size_t)n * PP + p;

        // CE over 81 classes: coalesced row read + wave log-sum-exp
        const float* row = pred_cls + idx * NCLS;
        float a = row[lane];
        float b = (lane < NCLS - 64) ? row[lane + 64] : -INFINITY;
        float mx = fmaxf(a, b);
#pragma unroll
        for (int d = 1; d < 64; d <<= 1) mx = fmaxf(mx, __shfl_xor(mx, d));
        float se = expf(a - mx) + ((lane < NCLS - 64) ? expf(b - mx) : 0.f);
#pragma unroll
        for (int d = 1; d < 64; d <<= 1) se += __shfl_xor(se, d);

        if (lane == 0) {
            int lb = labels[n * MM + bm];
            ce_s += mx + logf(se) - row[lb];
        } else if (lane == 1) {
            float4 pb = *(const float4*)(priors + (size_t)p * 4);
            const float* bb = boxes + ((size_t)n * MM + bm) * 4;
            float gx1 = bb[0], gy1 = bb[1], gx2 = bb[2], gy2 = bb[3];
            float pcx = (pb.x + pb.z) * 0.5f, pcy = (pb.y + pb.w) * 0.5f;
            float pw = pb.z - pb.x, ph = pb.w - pb.y;
            float g0 = ((gx1 + gx2) * 0.5f - pcx) / (pw / 10.0f);
            float g1 = ((gy1 + gy2) * 0.5f - pcy) / (ph / 10.0f);
            float g2 = logf((gx2 - gx1) / pw) * 5.0f;
            float g3 = logf((gy2 - gy1) / ph) * 5.0f;
            float4 pd = *(const float4*)(pred_boxes + idx * 4);
            loc_s += sl1(pd.x - g0) + sl1(pd.y - g1) + sl1(pd.z - g2) + sl1(pd.w - g3);
        } else if (lane == 2) {
            float o = pred_obj[idx];
            op_s += (o - 1.0f) * (o - 1.0f);
        }
    }
    if (lane == 0 && ce_s != 0.f)  atomicAdd(&sacc[0], ce_s);
    if (lane == 1 && loc_s != 0.f) atomicAdd(&sacc[1], loc_s);
    if (lane == 2 && op_s != 0.f)  atomicAdd(&sacc[2], op_s);
    __syncthreads();
    if (t == 0) {
        if (sacc[0] != 0.f) atomicAdd(&acc[1], sacc[0]);
        if (sacc[1] != 0.f) atomicAdd(&acc[0], sacc[1]);
        if (sacc[2] != 0.f) atomicAdd(&acc[2], sacc[2]);
    }
}

// ---------- Hard-negative mining: exact top-k sum via radix select ----------
extern "C" __global__ void __launch_bounds__(1024) k_hardneg(
    const float* __restrict__ pred_obj,
    const unsigned int* __restrict__ posbit,
    const int* __restrict__ pcnt,
    float* __restrict__ acc)
{
    const int n = blockIdx.x;
    const int t = threadIdx.x;
    const int wave = t >> 6;
    int k = pcnt[n] * 3;
    if (k > PP) k = PP;
    if (k <= 0) return;   // uniform
    const float* obj = pred_obj + (size_t)n * PP;
    const unsigned int* pb = posbit + n * PPW;

    __shared__ float wsum[16], wcnt[16];

    if (k >= PP) {
        float s = 0.f;
        for (int p = t; p < PP; p += 1024) {
            unsigned msk = (pb[p >> 5] >> (p & 31)) & 1u;
            float o = obj[p];
            s += msk ? 0.f : o * o;
        }
#pragma unroll
        for (int d = 32; d > 0; d >>= 1) s += __shfl_down(s, d);
        if ((t & 63) == 0) wsum[wave] = s;
        __syncthreads();
        if (t == 0) {
            float tot = 0.f;
            for (int i = 0; i < 16; i++) tot += wsum[i];
            atomicAdd(&acc[3], tot);
        }
        return;
    }

    __shared__ unsigned int hist[16][256];
    __shared__ unsigned int hsum[256];
    __shared__ unsigned int s_prefix;
    __shared__ int s_rem;

    unsigned prefix = 0; int rem = k;
    for (int pass = 0; pass < 4; ++pass) {
        const int shift = 24 - 8 * pass;
        for (int i = t; i < 16 * 256; i += 1024) ((unsigned*)hist)[i] = 0;
        __syncthreads();
        for (int p = t; p < PP; p += 1024) {
            unsigned msk = (pb[p >> 5] >> (p & 31)) & 1u;
            float o = obj[p];
            float v = msk ? 0.f : o * o;
            unsigned bb = __float_as_uint(v);
            if (pass == 0 || (bb >> (shift + 8)) == prefix)
                atomicAdd(&hist[wave][(bb >> shift) & 0xFFu], 1u);
        }
        __syncthreads();
        if (t < 256) {
            unsigned s2 = 0;
            for (int w2 = 0; w2 < 16; w2++) s2 += hist[w2][t];
            hsum[t] = s2;
        }
        __syncthreads();
        if (t == 0) {
            unsigned cum = 0; int d;
            for (d = 255; d > 0; --d) {
                if (cum + hsum[d] >= (unsigned)rem) break;
                cum += hsum[d];
            }
            s_prefix = (prefix << 8) | (unsigned)d;
            s_rem = rem - (int)cum;
        }
        __syncthreads();
        prefix = s_prefix; rem = s_rem;
        __syncthreads();
    }

    const unsigned thr = prefix;
    const float thrv = __uint_as_float(thr);
    float mysum = 0.f, mycnt = 0.f;
    for (int p = t; p < PP; p += 1024) {
        unsigned msk = (pb[p >> 5] >> (p & 31)) & 1u;
        float o = obj[p];
        float v = msk ? 0.f : o * o;
        if (__float_as_uint(v) > thr) { mysum += v; mycnt += 1.f; }
    }
#pragma unroll
    for (int d = 32; d > 0; d >>= 1) {
        mysum += __shfl_down(mysum, d);
        mycnt += __shfl_down(mycnt, d);
    }
    if ((t & 63) == 0) { wsum[wave] = mysum; wcnt[wave] = mycnt; }
    __syncthreads();
    if (t == 0) {
        float ts = 0.f, tc = 0.f;
        for (int i = 0; i < 16; i++) { ts += wsum[i]; tc += wcnt[i]; }
        atomicAdd(&acc[3], ts + ((float)k - tc) * thrv);
    }
}

// ---------- Finalize ----------
extern "C" __global__ void k_final(const float* __restrict__ acc,
                                   const int* __restrict__ pcnt,
                                   float* __restrict__ out)
{
    if (threadIdx.x == 0 && blockIdx.x == 0) {
        int np = 0, den = 0;
        for (int i = 0; i < NB; i++) {
            int c = pcnt[i];
            np += c;
            int k = c * 3; if (k > PP) k = PP;
            den += k;
        }
        float npf = (float)np;
        out[0] = acc[1] / npf + acc[2] / npf
               + acc[3] / fmaxf((float)den, 1.0f)
               + acc[0] / (npf * 4.0f);
    }
}

extern "C" void kernel_launch(void* const* d_in, const int* in_sizes, int n_in,
                              void* d_out, int out_size, void* d_ws, size_t ws_size,
                              hipStream_t stream) {
    const float* pred_boxes = (const float*)d_in[0];
    const float* pred_cls   = (const float*)d_in[1];
    const float* pred_obj   = (const float*)d_in[2];
    const float* priors     = (const float*)d_in[3];
    const float* boxes      = (const float*)d_in[4];
    const int*   labels     = (const int*)d_in[5];

    char* ws = (char*)d_ws;
    float* acc = (float*)(ws + WS_ACC);
    int* pcnt  = (int*)(ws + WS_PCNT);
    unsigned long long* bkey = (unsigned long long*)(ws + WS_BKEY);
    unsigned int* flist = (unsigned int*)(ws + WS_FLIST);
    unsigned int* posbit = (unsigned int*)(ws + WS_POSBIT);
    unsigned int* plist = (unsigned int*)(ws + WS_PLIST);

    k_zero<<<1, 256, 0, stream>>>((unsigned int*)d_ws);
    k_match<<<dim3(MBLK, NB), 256, 0, stream>>>(priors, boxes, bkey, posbit, plist, pcnt);
    k_force<<<1, 1024, 0, stream>>>(bkey, flist, posbit, plist, pcnt);
    k_pos<<<dim3(POSBLK_X, NB), 256, 0, stream>>>(pred_boxes, pred_cls, pred_obj,
                                                  priors, boxes, labels, plist, flist, pcnt, acc);
    k_hardneg<<<NB, 1024, 0, stream>>>(pred_obj, posbit, pcnt, acc);
    k_final<<<1, 64, 0, stream>>>(acc, pcnt, (float*)d_out);
}